// Round 1
// baseline (486.113 us; speedup 1.0000x reference)
//
#include <hip/hip_runtime.h>
#include <hip/hip_bf16.h>

#define NROWS 262144
#define CDIM  128
#define BN_EPS 1e-5f

typedef __attribute__((ext_vector_type(8))) short bf16x8;
typedef __attribute__((ext_vector_type(4))) float f32x4;

// round-to-nearest-even fp32 -> bf16 bits
static __device__ __forceinline__ unsigned int f2bf_rtn(float f) {
  unsigned int u = __float_as_uint(f);
  return (u + 0x7fffu + ((u >> 16) & 1u)) >> 16;
}
static __device__ __forceinline__ float bf2f(unsigned int b) {
  return __uint_as_float(b << 16);
}

// One kernel used for both GEMM stages.
// Computes h = in @ W^T + bias  (optionally in' = relu(in*scale+shift) first),
// writes h (fp32) to hout, accumulates per-column sum/sumsq into stats[0..255].
// Block = 256 threads (4 waves). Wave w owns output cols [32w, 32w+32) (2 MFMA
// j-tiles), block tile = 64 rows. Weights live in registers as bf16 hi/lo
// B-fragments for the whole kernel. A loaded global->reg in MFMA layout.
template <bool NORM>
__global__ void __launch_bounds__(256)
gemm_bn(const float* __restrict__ in, const float* __restrict__ W,
        const float* __restrict__ bias, const float* __restrict__ scsh,
        float* __restrict__ hout, float* __restrict__ stats)
{
  const int lane = threadIdx.x & 63;
  const int wave = threadIdx.x >> 6;
  const int l15  = lane & 15;
  const int lq   = lane >> 4;      // quarter-wave id = k-block
  const int wcol = wave * 32;

  // ---- B fragments: lane needs W[j = wcol + jt*16 + l15][k0 .. k0+7] ----
  bf16x8 bh[2][4], bl[2][4];
#pragma unroll
  for (int jt = 0; jt < 2; ++jt) {
    const float* wrow = W + (wcol + jt * 16 + l15) * CDIM;
#pragma unroll
    for (int ks = 0; ks < 4; ++ks) {
      const int k0 = ks * 32 + lq * 8;
      float4 w0 = *(const float4*)(wrow + k0);
      float4 w1 = *(const float4*)(wrow + k0 + 4);
      float wv[8] = {w0.x, w0.y, w0.z, w0.w, w1.x, w1.y, w1.z, w1.w};
#pragma unroll
      for (int e = 0; e < 8; ++e) {
        unsigned int h = f2bf_rtn(wv[e]);
        bh[jt][ks][e] = (short)h;
        bl[jt][ks][e] = (short)f2bf_rtn(wv[e] - bf2f(h));
      }
    }
  }

  const float bias0 = bias[wcol + l15];
  const float bias1 = bias[wcol + 16 + l15];

  float s0 = 0.f, s1 = 0.f, q0 = 0.f, q1 = 0.f;  // stats partials

  const int NT = NROWS / 64;
  for (int t = blockIdx.x; t < NT; t += gridDim.x) {
#pragma unroll
    for (int rt = 0; rt < 4; ++rt) {
      const int r0 = t * 64 + rt * 16;
      f32x4 acc0 = {0.f, 0.f, 0.f, 0.f};
      f32x4 acc1 = {0.f, 0.f, 0.f, 0.f};
#pragma unroll
      for (int ks = 0; ks < 4; ++ks) {
        const int k0 = ks * 32 + lq * 8;
        const float* ap = in + (r0 + l15) * CDIM + k0;
        float4 a0 = *(const float4*)(ap);
        float4 a1 = *(const float4*)(ap + 4);
        float av[8] = {a0.x, a0.y, a0.z, a0.w, a1.x, a1.y, a1.z, a1.w};
        if constexpr (NORM) {
          float4 c0 = *(const float4*)(scsh + k0);
          float4 c1 = *(const float4*)(scsh + k0 + 4);
          float4 d0 = *(const float4*)(scsh + CDIM + k0);
          float4 d1 = *(const float4*)(scsh + CDIM + k0 + 4);
          float cv[8] = {c0.x, c0.y, c0.z, c0.w, c1.x, c1.y, c1.z, c1.w};
          float dv[8] = {d0.x, d0.y, d0.z, d0.w, d1.x, d1.y, d1.z, d1.w};
#pragma unroll
          for (int e = 0; e < 8; ++e)
            av[e] = fmaxf(av[e] * cv[e] + dv[e], 0.f);
        }
        bf16x8 ah, al;
#pragma unroll
        for (int e = 0; e < 8; ++e) {
          unsigned int h = f2bf_rtn(av[e]);
          ah[e] = (short)h;
          al[e] = (short)f2bf_rtn(av[e] - bf2f(h));
        }
        // bf16x2 split product: A@B ~= Al@Bh + Ah@Bl + Ah@Bh  (fp32 accum)
        acc0 = __builtin_amdgcn_mfma_f32_16x16x32_bf16(al, bh[0][ks], acc0, 0, 0, 0);
        acc0 = __builtin_amdgcn_mfma_f32_16x16x32_bf16(ah, bl[0][ks], acc0, 0, 0, 0);
        acc0 = __builtin_amdgcn_mfma_f32_16x16x32_bf16(ah, bh[0][ks], acc0, 0, 0, 0);
        acc1 = __builtin_amdgcn_mfma_f32_16x16x32_bf16(al, bh[1][ks], acc1, 0, 0, 0);
        acc1 = __builtin_amdgcn_mfma_f32_16x16x32_bf16(ah, bl[1][ks], acc1, 0, 0, 0);
        acc1 = __builtin_amdgcn_mfma_f32_16x16x32_bf16(ah, bh[1][ks], acc1, 0, 0, 0);
      }
      // In-place stage (in == hout): all waves must finish reading this
      // 16-row stripe before any wave overwrites it. Uniform control flow.
      if constexpr (NORM) __syncthreads();

      // D layout (m89-verified): col = l15, row = lq*4 + r
      float* op = hout + (r0 + lq * 4) * CDIM + wcol + l15;
#pragma unroll
      for (int r = 0; r < 4; ++r) {
        float h0 = acc0[r] + bias0;
        float h1 = acc1[r] + bias1;
        s0 += h0; q0 += h0 * h0;
        s1 += h1; q1 += h1 * h1;
        op[r * CDIM] = h0;
        op[r * CDIM + 16] = h1;
      }
    }
  }

  // reduce quarters (lanes differing in bits 4,5 share a column)
  s0 += __shfl_xor(s0, 16); s0 += __shfl_xor(s0, 32);
  s1 += __shfl_xor(s1, 16); s1 += __shfl_xor(s1, 32);
  q0 += __shfl_xor(q0, 16); q0 += __shfl_xor(q0, 32);
  q1 += __shfl_xor(q1, 16); q1 += __shfl_xor(q1, 32);
  if (lane < 16) {
    atomicAdd(&stats[wcol + lane],        s0);
    atomicAdd(&stats[wcol + 16 + lane],   s1);
    atomicAdd(&stats[CDIM + wcol + lane],      q0);
    atomicAdd(&stats[CDIM + wcol + 16 + lane], q1);
  }
}

// stats (sum|sumsq) -> (scale|shift) per column
__global__ void __launch_bounds__(128)
bn_coeffs(const float* __restrict__ stats, const float* __restrict__ gamma,
          const float* __restrict__ beta, float* __restrict__ scsh)
{
  const int c = threadIdx.x;
  const float inv_n = 1.0f / (float)NROWS;
  float m  = stats[c] * inv_n;
  float v  = stats[CDIM + c] * inv_n - m * m;
  float sc = gamma[c] * rsqrtf(v + BN_EPS);
  scsh[c]        = sc;
  scsh[CDIM + c] = beta[c] - m * sc;
}

// out = relu(h2*scale+shift) + x   (in-place on d_out)
__global__ void __launch_bounds__(256)
finalize(const float4* __restrict__ h2, const float4* __restrict__ xin,
         const float* __restrict__ scsh, float4* __restrict__ outp)
{
  const int n4 = NROWS * CDIM / 4;
  for (int i = blockIdx.x * blockDim.x + threadIdx.x; i < n4;
       i += gridDim.x * blockDim.x) {
    const int c0 = (i << 2) & (CDIM - 1);
    float4 h  = h2[i];
    float4 xv = xin[i];
    float4 sc = *(const float4*)(scsh + c0);
    float4 sh = *(const float4*)(scsh + CDIM + c0);
    float4 o;
    o.x = fmaxf(h.x * sc.x + sh.x, 0.f) + xv.x;
    o.y = fmaxf(h.y * sc.y + sh.y, 0.f) + xv.y;
    o.z = fmaxf(h.z * sc.z + sh.z, 0.f) + xv.z;
    o.w = fmaxf(h.w * sc.w + sh.w, 0.f) + xv.w;
    outp[i] = o;
  }
}

extern "C" void kernel_launch(void* const* d_in, const int* in_sizes, int n_in,
                              void* d_out, int out_size, void* d_ws, size_t ws_size,
                              hipStream_t stream) {
  (void)in_sizes; (void)n_in; (void)out_size; (void)ws_size;
  const float* x   = (const float*)d_in[0];
  const float* W1  = (const float*)d_in[1];
  const float* b1  = (const float*)d_in[2];
  const float* g1  = (const float*)d_in[3];
  const float* be1 = (const float*)d_in[4];
  const float* W2  = (const float*)d_in[5];
  const float* b2  = (const float*)d_in[6];
  const float* g2  = (const float*)d_in[7];
  const float* be2 = (const float*)d_in[8];

  float* hbuf   = (float*)d_out;          // h1 then h2, in place
  float* stats1 = (float*)d_ws;           // [256] sum|sumsq
  float* stats2 = stats1 + 256;           // [256]
  float* scsh1  = stats1 + 512;           // [256] scale|shift
  float* scsh2  = stats1 + 768;           // [256]

  // ws is poisoned before every launch -> zero the accumulators
  hipMemsetAsync(d_ws, 0, 2048, stream);

  gemm_bn<false><<<1024, 256, 0, stream>>>(x, W1, b1, nullptr, hbuf, stats1);
  bn_coeffs<<<1, 128, 0, stream>>>(stats1, g1, be1, scsh1);
  gemm_bn<true><<<1024, 256, 0, stream>>>(hbuf, W2, b2, scsh1, hbuf, stats2);
  bn_coeffs<<<1, 128, 0, stream>>>(stats2, g2, be2, scsh2);
  finalize<<<2048, 256, 0, stream>>>((const float4*)hbuf, (const float4*)x,
                                     scsh2, (float4*)d_out);
}

// Round 4
// 430.058 us; speedup vs baseline: 1.1303x; 1.1303x over previous
//
#include <hip/hip_runtime.h>
#include <hip/hip_bf16.h>

#define NROWS 262144
#define CDIM  128
#define BN_EPS 1e-5f
#define GGRID 1024
#define SPB   (NROWS / 16 / GGRID)   // 16 stripes (16 rows each) per block

typedef __attribute__((ext_vector_type(8))) short bf16x8;
typedef __attribute__((ext_vector_type(4))) float f32x4;
#define LROW 136   // LDS row stride in shorts (128 data + 8 pad -> 272 B, 4-bank shift per row)

// round-to-nearest-even fp32 -> bf16 bits
static __device__ __forceinline__ unsigned int f2bf_rtn(float f) {
  unsigned int u = __float_as_uint(f);
  return (u + 0x7fffu + ((u >> 16) & 1u)) >> 16;
}
static __device__ __forceinline__ float bf2f(unsigned int b) {
  return __uint_as_float(b << 16);
}

// h = in @ W^T + bias   (NORM: in' = relu(in*scale+shift) first, in-place safe)
// A staged through LDS pre-split into bf16 hi/lo planes, double-buffered.
// Block = 256 thr (4 waves), wave w owns cols [32w,32w+32). 16-row stripes.
template <bool NORM>
__global__ void __launch_bounds__(256, 4)
gemm_bn(const float* __restrict__ in, const float* __restrict__ W,
        const float* __restrict__ bias, const float* __restrict__ scsh,
        float* __restrict__ hout, float* __restrict__ stats)
{
  __shared__ __align__(16) short lds[2][2][16][LROW];  // [buf][hi/lo][row][k]

  const int tid  = threadIdx.x;
  const int lane = tid & 63;
  const int wave = tid >> 6;
  const int l15  = lane & 15;
  const int lq   = lane >> 4;
  const int wcol = wave * 32;
  const int srow = tid >> 4;         // staging row 0..15
  const int sk0  = (tid & 15) * 8;   // staging k-chunk

  // ---- B fragments in registers for the whole kernel (hi/lo split) ----
  bf16x8 bh[2][4], bl[2][4];
#pragma unroll
  for (int jt = 0; jt < 2; ++jt) {
    const float* wrow = W + (wcol + jt * 16 + l15) * CDIM;
#pragma unroll
    for (int ks = 0; ks < 4; ++ks) {
      const int k0 = ks * 32 + lq * 8;
      f32x4 w0 = *(const f32x4*)(wrow + k0);
      f32x4 w1 = *(const f32x4*)(wrow + k0 + 4);
      float wv[8] = {w0.x,w0.y,w0.z,w0.w,w1.x,w1.y,w1.z,w1.w};
#pragma unroll
      for (int e = 0; e < 8; ++e) {
        unsigned int h = f2bf_rtn(wv[e]);
        bh[jt][ks][e] = (short)h;
        bl[jt][ks][e] = (short)f2bf_rtn(wv[e] - bf2f(h));
      }
    }
  }

  float scv[8], shv[8];
  if constexpr (NORM) {
#pragma unroll
    for (int e = 0; e < 8; ++e) {
      scv[e] = scsh[sk0 + e];
      shv[e] = scsh[CDIM + sk0 + e];
    }
  }

  const float bias0 = bias[wcol + l15];
  const float bias1 = bias[wcol + 16 + l15];
  float s0 = 0.f, s1 = 0.f, q0 = 0.f, q1 = 0.f;

  const int row0 = blockIdx.x * (SPB * 16);

  auto cvt_write = [&](int buf, f32x4 g0, f32x4 g1) {
    float av[8] = {g0.x,g0.y,g0.z,g0.w,g1.x,g1.y,g1.z,g1.w};
    if constexpr (NORM) {
#pragma unroll
      for (int e = 0; e < 8; ++e)
        av[e] = fmaxf(av[e] * scv[e] + shv[e], 0.f);
    }
    bf16x8 hi, lo;
#pragma unroll
    for (int e = 0; e < 8; ++e) {
      unsigned int h = f2bf_rtn(av[e]);
      hi[e] = (short)h;
      lo[e] = (short)f2bf_rtn(av[e] - bf2f(h));
    }
    *(bf16x8*)&lds[buf][0][srow][sk0] = hi;
    *(bf16x8*)&lds[buf][1][srow][sk0] = lo;
  };

  // prologue: stage stripe 0
  {
    const float* ap = in + (size_t)(row0 + srow) * CDIM + sk0;
    f32x4 g0 = *(const f32x4*)ap;
    f32x4 g1 = *(const f32x4*)(ap + 4);
    cvt_write(0, g0, g1);
  }
  __syncthreads();

  for (int s = 0; s < SPB; ++s) {
    const int cur = s & 1;
    const int r0 = row0 + s * 16;

    // issue next-stripe global loads EARLY (latency hides under MFMA phase)
    f32x4 g0 = {0,0,0,0}, g1 = {0,0,0,0};
    const bool more = (s + 1 < SPB);   // block-uniform
    if (more) {
      const float* ap = in + (size_t)(r0 + 16 + srow) * CDIM + sk0;
      g0 = *(const f32x4*)ap;
      g1 = *(const f32x4*)(ap + 4);
    }

    // compute stripe s from lds[cur]
    f32x4 acc0 = {0.f,0.f,0.f,0.f};
    f32x4 acc1 = {0.f,0.f,0.f,0.f};
#pragma unroll
    for (int ks = 0; ks < 4; ++ks) {
      const int kc = ks * 32 + lq * 8;
      bf16x8 ah = *(const bf16x8*)&lds[cur][0][l15][kc];
      bf16x8 al = *(const bf16x8*)&lds[cur][1][l15][kc];
      acc0 = __builtin_amdgcn_mfma_f32_16x16x32_bf16(al, bh[0][ks], acc0, 0, 0, 0);
      acc0 = __builtin_amdgcn_mfma_f32_16x16x32_bf16(ah, bl[0][ks], acc0, 0, 0, 0);
      acc0 = __builtin_amdgcn_mfma_f32_16x16x32_bf16(ah, bh[0][ks], acc0, 0, 0, 0);
      acc1 = __builtin_amdgcn_mfma_f32_16x16x32_bf16(al, bh[1][ks], acc1, 0, 0, 0);
      acc1 = __builtin_amdgcn_mfma_f32_16x16x32_bf16(ah, bl[1][ks], acc1, 0, 0, 0);
      acc1 = __builtin_amdgcn_mfma_f32_16x16x32_bf16(ah, bh[1][ks], acc1, 0, 0, 0);
    }

    // convert + write next stripe into the buffer freed at last barrier
    if (more) cvt_write(cur ^ 1, g0, g1);
    __syncthreads();

    // store stripe s (post-barrier: every wave consumed stripe-s global reads
    // before barrier(s-1), and all lds[cur] reads are done -> in-place safe)
    float* op = hout + (size_t)(r0 + lq * 4) * CDIM + wcol + l15;
#pragma unroll
    for (int r = 0; r < 4; ++r) {
      float h0 = acc0[r] + bias0;
      float h1 = acc1[r] + bias1;
      s0 += h0; q0 += h0 * h0;
      s1 += h1; q1 += h1 * h1;
      op[r * CDIM] = h0;
      op[r * CDIM + 16] = h1;
    }
  }

  // reduce quarters (lanes differing in bits 4,5 share a column)
  s0 += __shfl_xor(s0, 16); s0 += __shfl_xor(s0, 32);
  s1 += __shfl_xor(s1, 16); s1 += __shfl_xor(s1, 32);
  q0 += __shfl_xor(q0, 16); q0 += __shfl_xor(q0, 32);
  q1 += __shfl_xor(q1, 16); q1 += __shfl_xor(q1, 32);
  if (lane < 16) {
    atomicAdd(&stats[wcol + lane],             s0);
    atomicAdd(&stats[wcol + 16 + lane],        s1);
    atomicAdd(&stats[CDIM + wcol + lane],      q0);
    atomicAdd(&stats[CDIM + wcol + 16 + lane], q1);
  }
}

// stats (sum|sumsq) -> (scale|shift) per column
__global__ void __launch_bounds__(128)
bn_coeffs(const float* __restrict__ stats, const float* __restrict__ gamma,
          const float* __restrict__ beta, float* __restrict__ scsh)
{
  const int c = threadIdx.x;
  const float inv_n = 1.0f / (float)NROWS;
  float m  = stats[c] * inv_n;
  float v  = stats[CDIM + c] * inv_n - m * m;
  float sc = gamma[c] * rsqrtf(v + BN_EPS);
  scsh[c]        = sc;
  scsh[CDIM + c] = beta[c] - m * sc;
}

// out = relu(h2*scale+shift) + x   (in-place on d_out); 32 B/lane/iter
__global__ void __launch_bounds__(256)
finalize(const f32x4* __restrict__ h2, const f32x4* __restrict__ xin,
         const float* __restrict__ scsh, f32x4* __restrict__ outp)
{
  const int n4 = NROWS * CDIM / 4;
  const int stride = gridDim.x * blockDim.x * 2;
  for (int i = (blockIdx.x * blockDim.x + threadIdx.x) * 2; i < n4; i += stride) {
    f32x4 hA = h2[i], hB = h2[i + 1];
    f32x4 xA = xin[i], xB = xin[i + 1];
    const int c0 = (i << 2) & (CDIM - 1);
    f32x4 scA = *(const f32x4*)(scsh + c0);
    f32x4 scB = *(const f32x4*)(scsh + c0 + 4);
    f32x4 shA = *(const f32x4*)(scsh + CDIM + c0);
    f32x4 shB = *(const f32x4*)(scsh + CDIM + c0 + 4);
    f32x4 oA, oB;
    oA.x = fmaxf(hA.x * scA.x + shA.x, 0.f) + xA.x;
    oA.y = fmaxf(hA.y * scA.y + shA.y, 0.f) + xA.y;
    oA.z = fmaxf(hA.z * scA.z + shA.z, 0.f) + xA.z;
    oA.w = fmaxf(hA.w * scA.w + shA.w, 0.f) + xA.w;
    oB.x = fmaxf(hB.x * scB.x + shB.x, 0.f) + xB.x;
    oB.y = fmaxf(hB.y * scB.y + shB.y, 0.f) + xB.y;
    oB.z = fmaxf(hB.z * scB.z + shB.z, 0.f) + xB.z;
    oB.w = fmaxf(hB.w * scB.w + shB.w, 0.f) + xB.w;
    __builtin_nontemporal_store(oA, &outp[i]);
    __builtin_nontemporal_store(oB, &outp[i + 1]);
  }
}

extern "C" void kernel_launch(void* const* d_in, const int* in_sizes, int n_in,
                              void* d_out, int out_size, void* d_ws, size_t ws_size,
                              hipStream_t stream) {
  (void)in_sizes; (void)n_in; (void)out_size; (void)ws_size;
  const float* x   = (const float*)d_in[0];
  const float* W1  = (const float*)d_in[1];
  const float* b1  = (const float*)d_in[2];
  const float* g1  = (const float*)d_in[3];
  const float* be1 = (const float*)d_in[4];
  const float* W2  = (const float*)d_in[5];
  const float* b2  = (const float*)d_in[6];
  const float* g2  = (const float*)d_in[7];
  const float* be2 = (const float*)d_in[8];

  float* hbuf   = (float*)d_out;          // h1 then h2, in place
  float* stats1 = (float*)d_ws;           // [256] sum|sumsq
  float* stats2 = stats1 + 256;           // [256]
  float* scsh1  = stats1 + 512;           // [256] scale|shift
  float* scsh2  = stats1 + 768;           // [256]

  (void)hipMemsetAsync(d_ws, 0, 2048, stream);  // zero the stats accumulators

  gemm_bn<false><<<GGRID, 256, 0, stream>>>(x, W1, b1, nullptr, hbuf, stats1);
  bn_coeffs<<<1, 128, 0, stream>>>(stats1, g1, be1, scsh1);
  gemm_bn<true><<<GGRID, 256, 0, stream>>>(hbuf, W2, b2, scsh1, hbuf, stats2);
  bn_coeffs<<<1, 128, 0, stream>>>(stats2, g2, be2, scsh2);
  finalize<<<4096, 256, 0, stream>>>((const f32x4*)hbuf, (const f32x4*)x,
                                     scsh2, (f32x4*)d_out);
}